// Round 1
// baseline (75.862 us; speedup 1.0000x reference)
//
#include <hip/hip_runtime.h>

#define NB 65536
#define NJ 24
#define NTRK 6

__device__ __forceinline__ void rpy2R(float r, float p, float y, float* R) {
    float cr, sr, cp, sp, cy, sy;
    __sincosf(r, &sr, &cr);  // fast versions are ~2^-21 accurate; threshold is 0.37
    sr = sinf(r); cr = cosf(r);   // use precise anyway (runs only 24x/block)
    sp = sinf(p); cp = cosf(p);
    sy = sinf(y); cy = cosf(y);
    R[0] = cy * cp; R[1] = cy * sp * sr - sy * cr; R[2] = cy * sp * cr + sy * sr;
    R[3] = sy * cp; R[4] = sy * sp * sr + cy * cr; R[5] = sy * sp * cr - cy * sr;
    R[6] = -sp;     R[7] = cp * sr;                R[8] = cp * cr;
}

// C = A o B  (SE3 compose): Rc = Ra*Rb, pc = Ra*pb + pa.  Rc/pc must not alias Ra/pa.
__device__ __forceinline__ void compose(const float* Ra, const float* pa,
                                        const float* Rb, const float* pb,
                                        float* Rc, float* pc) {
#pragma unroll
    for (int i = 0; i < 3; i++) {
        float a0 = Ra[i*3+0], a1 = Ra[i*3+1], a2 = Ra[i*3+2];
        Rc[i*3+0] = a0*Rb[0] + a1*Rb[3] + a2*Rb[6];
        Rc[i*3+1] = a0*Rb[1] + a1*Rb[4] + a2*Rb[7];
        Rc[i*3+2] = a0*Rb[2] + a1*Rb[5] + a2*Rb[8];
        pc[i]     = a0*pb[0] + a1*pb[1] + a2*pb[2] + pa[i];
    }
}

__global__ __launch_bounds__(256) void fk_kernel(
    const float* __restrict__ rev_q,   const float* __restrict__ pri_q,
    const float* __restrict__ p_off,   const float* __restrict__ rpy_off,
    const float* __restrict__ rev_axis,const float* __restrict__ pri_axis,
    const float* __restrict__ p_trk,   const float* __restrict__ rpy_trk,
    float* __restrict__ out_track, float* __restrict__ out_joint)
{
    // Per-joint static data, computed once per block.
    __shared__ float s_offR[NJ][9];
    __shared__ float s_offp[NJ][3];
    __shared__ float s_trkR[NJ][9];
    __shared__ float s_trkp[NJ][3];
    __shared__ float s_ar[NJ][4];   // normalized rev axis (x,y,z) + dot(a,a)
    __shared__ float s_ap[NJ][3];   // raw pri axis

    int j = threadIdx.x;
    if (j < NJ) {
        float R[9];
        rpy2R(rpy_off[j*3+0], rpy_off[j*3+1], rpy_off[j*3+2], R);
#pragma unroll
        for (int k = 0; k < 9; k++) s_offR[j][k] = R[k];
        s_offp[j][0] = p_off[j*3+0]; s_offp[j][1] = p_off[j*3+1]; s_offp[j][2] = p_off[j*3+2];

        rpy2R(rpy_trk[j*3+0], rpy_trk[j*3+1], rpy_trk[j*3+2], R);
#pragma unroll
        for (int k = 0; k < 9; k++) s_trkR[j][k] = R[k];
        s_trkp[j][0] = p_trk[j*3+0]; s_trkp[j][1] = p_trk[j*3+1]; s_trkp[j][2] = p_trk[j*3+2];

        float ax = rev_axis[j*3+0], ay = rev_axis[j*3+1], az = rev_axis[j*3+2];
        float n = sqrtf(ax*ax + ay*ay + az*az) + 1e-8f;   // matches ref: axis/(norm+EPS)
        ax /= n; ay /= n; az /= n;
        s_ar[j][0] = ax; s_ar[j][1] = ay; s_ar[j][2] = az;
        s_ar[j][3] = ax*ax + ay*ay + az*az;

        s_ap[j][0] = pri_axis[j*3+0]; s_ap[j][1] = pri_axis[j*3+1]; s_ap[j][2] = pri_axis[j*3+2];
    }
    __syncthreads();

    int b = blockIdx.x * blockDim.x + threadIdx.x;

    // Load the 24 revolute + 24 prismatic q values as float4s (rows are 96B, 16B aligned).
    float rq[NJ], pq[NJ];
    const float4* rq4 = (const float4*)(rev_q + (size_t)b * NJ);
    const float4* pq4 = (const float4*)(pri_q + (size_t)b * NJ);
#pragma unroll
    for (int k = 0; k < NJ/4; k++) {
        float4 v = rq4[k];
        rq[4*k+0] = v.x; rq[4*k+1] = v.y; rq[4*k+2] = v.z; rq[4*k+3] = v.w;
        float4 w = pq4[k];
        pq[4*k+0] = w.x; pq[4*k+1] = w.y; pq[4*k+2] = w.z; pq[4*k+3] = w.w;
    }

    // Running transform (identity).
    float oR[9] = {1.f,0.f,0.f, 0.f,1.f,0.f, 0.f,0.f,1.f};
    float op[3] = {0.f,0.f,0.f};

    float4* tbase = (float4*)out_track + (size_t)b * NTRK * 4;
    float4* jbase = (float4*)out_joint + (size_t)b * NJ * 4;

#pragma unroll
    for (int jj = 0; jj < NJ; jj++) {
        // pre = out o T_offset[jj]   (this is the recorded JointSE3)
        float pR[9], pp[3];
        compose(oR, op, &s_offR[jj][0], &s_offp[jj][0], pR, pp);

        jbase[jj*4+0] = make_float4(pR[0], pR[1], pR[2], pp[0]);
        jbase[jj*4+1] = make_float4(pR[3], pR[4], pR[5], pp[1]);
        jbase[jj*4+2] = make_float4(pR[6], pR[7], pR[8], pp[2]);
        jbase[jj*4+3] = make_float4(0.f, 0.f, 0.f, 1.f);

        // Joint motion: Rodrigues rotation + prismatic translation.
        float s, c;
        s = __sinf(rq[jj]); c = __cosf(rq[jj]);
        float c1 = 1.0f - c;
        float ax = s_ar[jj][0], ay = s_ar[jj][1], az = s_ar[jj][2], dot = s_ar[jj][3];
        float jR[9];
        jR[0] = 1.f + c1*(ax*ax - dot);  jR[1] = -s*az + c1*ax*ay;        jR[2] =  s*ay + c1*ax*az;
        jR[3] =  s*az + c1*ax*ay;        jR[4] = 1.f + c1*(ay*ay - dot);  jR[5] = -s*ax + c1*ay*az;
        jR[6] = -s*ay + c1*ax*az;        jR[7] =  s*ax + c1*ay*az;        jR[8] = 1.f + c1*(az*az - dot);

        float q = pq[jj];
        float v0 = q * s_ap[jj][0], v1 = q * s_ap[jj][1], v2 = q * s_ap[jj][2];
        float jp[3];
        jp[0] = jR[0]*v0 + jR[1]*v1 + jR[2]*v2;
        jp[1] = jR[3]*v0 + jR[4]*v1 + jR[5]*v2;
        jp[2] = jR[6]*v0 + jR[7]*v1 + jR[8]*v2;

        // post = pre o T_joint  -> becomes the running transform
        compose(pR, pp, jR, jp, oR, op);

        if ((jj & 3) == 3) {   // tracked joints: 3,7,11,15,19,23 -> slots 0..5
            float tR[9], tp[3];
            compose(oR, op, &s_trkR[jj][0], &s_trkp[jj][0], tR, tp);
            int t = jj >> 2;
            tbase[t*4+0] = make_float4(tR[0], tR[1], tR[2], tp[0]);
            tbase[t*4+1] = make_float4(tR[3], tR[4], tR[5], tp[1]);
            tbase[t*4+2] = make_float4(tR[6], tR[7], tR[8], tp[2]);
            tbase[t*4+3] = make_float4(0.f, 0.f, 0.f, 1.f);
        }
    }
}

extern "C" void kernel_launch(void* const* d_in, const int* in_sizes, int n_in,
                              void* d_out, int out_size, void* d_ws, size_t ws_size,
                              hipStream_t stream) {
    const float* rev_q    = (const float*)d_in[0];
    const float* pri_q    = (const float*)d_in[1];
    const float* p_off    = (const float*)d_in[2];
    const float* rpy_off  = (const float*)d_in[3];
    const float* rev_axis = (const float*)d_in[4];
    const float* pri_axis = (const float*)d_in[5];
    const float* p_trk    = (const float*)d_in[6];
    const float* rpy_trk  = (const float*)d_in[7];

    float* out = (float*)d_out;
    float* out_track = out;                                    // (B, 6, 4, 4)
    float* out_joint = out + (size_t)NB * NTRK * 16;           // (B, 24, 4, 4)

    dim3 grid(NB / 256), block(256);
    hipLaunchKernelGGL(fk_kernel, grid, block, 0, stream,
                       rev_q, pri_q, p_off, rpy_off, rev_axis, pri_axis,
                       p_trk, rpy_trk, out_track, out_joint);
}

// Round 2
// 64.255 us; speedup vs baseline: 1.1806x; 1.1806x over previous
//
#include <hip/hip_runtime.h>

#define NB 65536
#define NJ 24
#define NTRK 6
#define BPB 8      // batches per 256-thread block
#define GRP 32     // lanes per batch group (24 active)

__device__ __forceinline__ void rpy2R(float r, float p, float y, float* R) {
    float cr = cosf(r), sr = sinf(r);
    float cp = cosf(p), sp = sinf(p);
    float cy = cosf(y), sy = sinf(y);
    R[0] = cy * cp; R[1] = cy * sp * sr - sy * cr; R[2] = cy * sp * cr + sy * sr;
    R[3] = sy * cp; R[4] = sy * sp * sr + cy * cr; R[5] = sy * sp * cr - cy * sr;
    R[6] = -sp;     R[7] = cp * sr;                R[8] = cp * cr;
}

// C = A o B (SE3): Rc = Ra*Rb, pc = Ra*pb + pa.  C must not alias A or B.
__device__ __forceinline__ void compose(const float* Ra, const float* pa,
                                        const float* Rb, const float* pb,
                                        float* Rc, float* pc) {
#pragma unroll
    for (int i = 0; i < 3; i++) {
        float a0 = Ra[i*3+0], a1 = Ra[i*3+1], a2 = Ra[i*3+2];
        Rc[i*3+0] = a0*Rb[0] + a1*Rb[3] + a2*Rb[6];
        Rc[i*3+1] = a0*Rb[1] + a1*Rb[4] + a2*Rb[7];
        Rc[i*3+2] = a0*Rb[2] + a1*Rb[5] + a2*Rb[8];
        pc[i]     = a0*pb[0] + a1*pb[1] + a2*pb[2] + pa[i];
    }
}

__global__ __launch_bounds__(256, 4) void fk_scan_kernel(
    const float* __restrict__ rev_q,    const float* __restrict__ pri_q,
    const float* __restrict__ p_off,    const float* __restrict__ rpy_off,
    const float* __restrict__ rev_axis, const float* __restrict__ pri_axis,
    const float* __restrict__ p_trk,    const float* __restrict__ rpy_trk,
    float* __restrict__ out_track, float* __restrict__ out_joint)
{
    __shared__ float s_j[BPB * NJ * 16];    // 12 KB, exact output layout
    __shared__ float s_t[BPB * NTRK * 16];  //  3 KB

    const int tid = threadIdx.x;
    const int g   = tid & (GRP - 1);          // lane within batch group
    const int bl  = tid >> 5;                 // batch within block
    const int b   = blockIdx.x * BPB + bl;
    const int j   = (g < NJ) ? g : (NJ - 1);  // clamp padding lanes (no OOB)
    const bool active = (g < NJ);

    // ---- per-lane joint statics (tiny, L2-cached) ----
    float ToR[9], Top[3];
    rpy2R(rpy_off[j*3+0], rpy_off[j*3+1], rpy_off[j*3+2], ToR);
    Top[0] = p_off[j*3+0]; Top[1] = p_off[j*3+1]; Top[2] = p_off[j*3+2];

    float ax = rev_axis[j*3+0], ay = rev_axis[j*3+1], az = rev_axis[j*3+2];
    float n = sqrtf(ax*ax + ay*ay + az*az) + 1e-8f;   // ref: axis/(norm+EPS)
    ax /= n; ay /= n; az /= n;
    float adot = ax*ax + ay*ay + az*az;

    // ---- per-(b,j) joint transform Tj ----
    float qr = rev_q[(size_t)b * NJ + j];
    float qp = pri_q[(size_t)b * NJ + j];
    float s = __sinf(qr), c = __cosf(qr), c1 = 1.0f - c;
    float jR[9];
    jR[0] = 1.f + c1*(ax*ax - adot);  jR[1] = -s*az + c1*ax*ay;        jR[2] =  s*ay + c1*ax*az;
    jR[3] =  s*az + c1*ax*ay;         jR[4] = 1.f + c1*(ay*ay - adot); jR[5] = -s*ax + c1*ay*az;
    jR[6] = -s*ay + c1*ax*az;         jR[7] =  s*ax + c1*ay*az;        jR[8] = 1.f + c1*(az*az - adot);
    float v0 = qp * pri_axis[j*3+0], v1 = qp * pri_axis[j*3+1], v2 = qp * pri_axis[j*3+2];
    float jp[3];
    jp[0] = jR[0]*v0 + jR[1]*v1 + jR[2]*v2;
    jp[1] = jR[3]*v0 + jR[4]*v1 + jR[5]*v2;
    jp[2] = jR[6]*v0 + jR[7]*v1 + jR[8]*v2;

    // ---- L_j = T_offset[j] o T_joint[j];  M = inclusive prefix product ----
    float MR[9], Mp[3];
    compose(ToR, Top, jR, jp, MR, Mp);

#pragma unroll
    for (int sft = 1; sft < NJ; sft <<= 1) {   // 1,2,4,8,16
        float fR[9], fp[3];
#pragma unroll
        for (int k = 0; k < 9; k++) fR[k] = __shfl_up(MR[k], sft, GRP);
#pragma unroll
        for (int k = 0; k < 3; k++) fp[k] = __shfl_up(Mp[k], sft, GRP);
        if (g >= sft) {
            float nR[9], np[3];
            compose(fR, fp, MR, Mp, nR, np);   // earlier-index operand on the left
#pragma unroll
            for (int k = 0; k < 9; k++) MR[k] = nR[k];
#pragma unroll
            for (int k = 0; k < 3; k++) Mp[k] = np[k];
        }
    }

    // ---- exclusive prefix E = M_{j-1} (identity at j=0) ----
    float ER[9], Ep[3];
#pragma unroll
    for (int k = 0; k < 9; k++) ER[k] = __shfl_up(MR[k], 1, GRP);
#pragma unroll
    for (int k = 0; k < 3; k++) Ep[k] = __shfl_up(Mp[k], 1, GRP);
    if (g == 0) {
        ER[0]=1.f; ER[1]=0.f; ER[2]=0.f; ER[3]=0.f; ER[4]=1.f; ER[5]=0.f;
        ER[6]=0.f; ER[7]=0.f; ER[8]=1.f; Ep[0]=0.f; Ep[1]=0.f; Ep[2]=0.f;
    }

    // ---- pre_j (JointSE3) = E o T_offset ----
    float PR[9], Pp[3];
    compose(ER, Ep, ToR, Top, PR, Pp);

    if (active) {
        // rotated row order spreads LDS banks across lanes
        float4* dst = (float4*)&s_j[(bl * NJ + g) * 16];
#pragma unroll
        for (int r0 = 0; r0 < 4; r0++) {
            int r = (r0 + g) & 3;
            float4 v = (r < 3) ? make_float4(PR[r*3+0], PR[r*3+1], PR[r*3+2], Pp[r])
                               : make_float4(0.f, 0.f, 0.f, 1.f);
            dst[r] = v;
        }
        if ((g & 3) == 3) {   // tracked joints 3,7,...,23 -> slots 0..5
            float TtR[9], Ttp[3];
            rpy2R(rpy_trk[j*3+0], rpy_trk[j*3+1], rpy_trk[j*3+2], TtR);
            Ttp[0] = p_trk[j*3+0]; Ttp[1] = p_trk[j*3+1]; Ttp[2] = p_trk[j*3+2];
            float TR[9], Tp[3];
            compose(MR, Mp, TtR, Ttp, TR, Tp);   // post o T_track
            float4* td = (float4*)&s_t[(bl * NTRK + (g >> 2)) * 16];
#pragma unroll
            for (int r0 = 0; r0 < 4; r0++) {
                int r = (r0 + g) & 3;
                float4 v = (r < 3) ? make_float4(TR[r*3+0], TR[r*3+1], TR[r*3+2], Tp[r])
                                   : make_float4(0.f, 0.f, 0.f, 1.f);
                td[r] = v;
            }
        }
    }
    __syncthreads();

    // ---- coalesced flush: block chunks are contiguous in global memory ----
    const float4* sj4 = (const float4*)s_j;
    float4* oj = (float4*)out_joint + (size_t)blockIdx.x * (BPB * NJ * 4);
#pragma unroll
    for (int k = 0; k < 3; k++) {
        int idx = tid + 256 * k;               // 768 float4 per block
        oj[idx] = sj4[idx];
    }
    const float4* st4 = (const float4*)s_t;
    float4* ot = (float4*)out_track + (size_t)blockIdx.x * (BPB * NTRK * 4);
    if (tid < BPB * NTRK * 4) ot[tid] = st4[tid];  // 192 float4 per block
}

extern "C" void kernel_launch(void* const* d_in, const int* in_sizes, int n_in,
                              void* d_out, int out_size, void* d_ws, size_t ws_size,
                              hipStream_t stream) {
    const float* rev_q    = (const float*)d_in[0];
    const float* pri_q    = (const float*)d_in[1];
    const float* p_off    = (const float*)d_in[2];
    const float* rpy_off  = (const float*)d_in[3];
    const float* rev_axis = (const float*)d_in[4];
    const float* pri_axis = (const float*)d_in[5];
    const float* p_trk    = (const float*)d_in[6];
    const float* rpy_trk  = (const float*)d_in[7];

    float* out = (float*)d_out;
    float* out_track = out;                           // (B, 6, 4, 4)
    float* out_joint = out + (size_t)NB * NTRK * 16;  // (B, 24, 4, 4)

    dim3 grid(NB / BPB), block(256);
    hipLaunchKernelGGL(fk_scan_kernel, grid, block, 0, stream,
                       rev_q, pri_q, p_off, rpy_off, rev_axis, pri_axis,
                       p_trk, rpy_trk, out_track, out_joint);
}